// Round 6
// baseline (1116.808 us; speedup 1.0000x reference)
//
#include <hip/hip_runtime.h>
#include <hip/hip_bf16.h>

typedef unsigned short u16;
typedef unsigned int u32;
typedef unsigned long long u64;
typedef _Float16 half2v __attribute__((ext_vector_type(2)));

#define LSEQ 256

// ---------------- ws float-offsets ----------------
constexpr int XW_F  = 0;        // [b][t][1024] fp32 (x@W + b), fwd
constexpr int XW_B  = 524288;   // bwd
constexpr int HF_O  = 1048576;  // h_fwd [t][unit*2 + b] fp32
constexpr int HB_O  = 1179648;  // h_bwd [t][unit*2 + b] fp32 (t-indexed now)
constexpr int PEH_O = 1703936;  // [512]
constexpr int QEH_O = 1704448;  // [512]
constexpr int PHH_O = 1704960;  // [512][24]
constexpr int QHH_O = 1717248;
constexpr int PTT_O = 1729536;
constexpr int QTT_O = 1741824;

__device__ __forceinline__ float b2f(u16 u) {
  u32 x = ((u32)u) << 16; float f;
  __builtin_memcpy(&f, &x, 4); return f;
}
__device__ __forceinline__ u16 f2b(float f) {
  u32 x; __builtin_memcpy(&x, &f, 4);
  u32 r = (x + 0x7fffu + ((x >> 16) & 1u)) >> 16;
  return (u16)r;
}
__device__ __forceinline__ float sigm(float x) {
  return __builtin_amdgcn_rcpf(1.f + __expf(-x));
}
__device__ __forceinline__ float tanh_fast(float x) {
  return 2.f * __builtin_amdgcn_rcpf(1.f + __expf(-2.f * x)) - 1.f;
}
// dtype probe: wave-uniform. fp32 storage: bit14 is a mantissa bit (~50% set
// over 64 samples). bf16 storage: bit14 = exp MSB of low bf16 -> 0 hits.
__device__ __forceinline__ bool detect_f32(const void* etab) {
  u32 w = ((const u32*)etab)[threadIdx.x & 63];
  u64 m = __ballot((w & 0x4000u) != 0);
  return __popcll(m) >= 16;
}
__device__ __forceinline__ float ldf(const void* p, int i, bool f32m) {
  return f32m ? ((const float*)p)[i] : b2f(((const u16*)p)[i]);
}
__device__ __forceinline__ u32 packh(float lo, float hi) {
  half2v v; v.x = (_Float16)lo; v.y = (_Float16)hi;
  u32 r; __builtin_memcpy(&r, &v, 4); return r;
}
__device__ __forceinline__ float dot2f(u32 a, u32 b, float c) {
  half2v av, bv;
  __builtin_memcpy(&av, &a, 4); __builtin_memcpy(&bv, &b, 4);
#if __has_builtin(__builtin_amdgcn_fdot2)
  return __builtin_amdgcn_fdot2(av, bv, c, false);
#else
  return c + (float)av.x * (float)bv.x + (float)av.y * (float)bv.y;
#endif
}

// ---------------- k_embed_xw: embeddings + x@W (+b), both dirs ----------------
// grid 256 = 64 rowgroups x {dir,colhalf}; 8 rows, 512 cols per block.
__global__ __launch_bounds__(256) void k_embed_xw(
    const int* __restrict__ toks, const int* __restrict__ wrds,
    const void* __restrict__ etab, const void* __restrict__ wtab,
    const void* __restrict__ Wf, const void* __restrict__ bf_,
    const void* __restrict__ Wb, const void* __restrict__ bb_,
    float* __restrict__ ws)
{
  __shared__ float xs[8][256];
  const int tid = threadIdx.x, bx = blockIdx.x;
  const int rg = bx >> 2, part = bx & 3, dir = part >> 1, ch = part & 1;
  const bool f32m = detect_f32(etab);
  for (int rr = 0; rr < 8; rr++) {
    const int row = rg * 8 + rr;
    const int id = toks[row], wid = wrds[row];
    xs[rr][tid] = (tid < 128) ? ldf(etab, id * 128 + tid, f32m)
                              : ldf(wtab, wid * 128 + (tid - 128), f32m);
  }
  __syncthreads();
  const void* W = dir ? Wb : Wf;
  const void* bb = dir ? bb_ : bf_;
  const int c0 = ch * 512 + 2 * tid;
  float acc[8][2];
#pragma unroll
  for (int rr = 0; rr < 8; rr++) { acc[rr][0] = 0.f; acc[rr][1] = 0.f; }
  if (f32m) {
    const float2* W2 = (const float2*)W;
    for (int k = 0; k < 256; k++) {
      const float2 w = W2[k * 512 + (c0 >> 1)];
#pragma unroll
      for (int rr = 0; rr < 8; rr++) {
        const float x = xs[rr][k];
        acc[rr][0] = fmaf(x, w.x, acc[rr][0]);
        acc[rr][1] = fmaf(x, w.y, acc[rr][1]);
      }
    }
  } else {
    const u32* W2 = (const u32*)W;
    for (int k = 0; k < 256; k++) {
      const u32 v = W2[k * 512 + (c0 >> 1)];
      const float wx = b2f(v & 0xffff), wy = b2f(v >> 16);
#pragma unroll
      for (int rr = 0; rr < 8; rr++) {
        const float x = xs[rr][k];
        acc[rr][0] = fmaf(x, wx, acc[rr][0]);
        acc[rr][1] = fmaf(x, wy, acc[rr][1]);
      }
    }
  }
  const float b0 = ldf(bb, c0, f32m), b1 = ldf(bb, c0 + 1, f32m);
  float* xwb = ws + (dir ? XW_B : XW_F);
#pragma unroll
  for (int rr = 0; rr < 8; rr++) {
    const int row = rg * 8 + rr;
    float2 o = make_float2(acc[rr][0] + b0, acc[rr][1] + b1);
    *(float2*)(xwb + row * 1024 + c0) = o;
  }
}

// ---------------- k_lstm: 4 independent WGs, one per (dir,batch) ----------------
// Each WG owns the FULL 256-unit recurrence of one chain: zero cross-WG sync.
// U (256x1024) as fp16 pairs along k: kp in [0,96) in VGPRs (384 u32),
// kp in [96,128) in LDS (128 KB). h kept as fp16 pairs in LDS; z via LDS.
// Inner op: v_dot2_f32_f16 (fp32 accumulate).
__global__ __launch_bounds__(256, 1) void k_lstm(
    const int* __restrict__ toks,
    const void* __restrict__ Uf_raw, const void* __restrict__ Ub_raw,
    const void* __restrict__ etab, float* __restrict__ ws)
{
  __shared__ u32 ulds[32][1024];   // U kp 96..127, 128 KB
  __shared__ float zsh[1024];
  __shared__ u32 hp[128];          // h as fp16 pairs
  __shared__ int msk[256];
  const int tid = threadIdx.x;
  const int dir = blockIdx.x >> 1, b = blockIdx.x & 1;
  const bool f32m = detect_f32(etab);
  const void* Uraw = dir ? Ub_raw : Uf_raw;
  const float* xw = ws + (dir ? XW_B : XW_F) + b * 262144;
  float* hout = ws + (dir ? HB_O : HF_O);
  const int c0 = 4 * tid;

  u32 ur[96][4];
  if (f32m) {
    const float* U = (const float*)Uraw;
#pragma unroll
    for (int kp = 0; kp < 96; kp++) {
      const float4 r0 = *(const float4*)(U + (2 * kp) * 1024 + c0);
      const float4 r1 = *(const float4*)(U + (2 * kp + 1) * 1024 + c0);
      ur[kp][0] = packh(r0.x, r1.x); ur[kp][1] = packh(r0.y, r1.y);
      ur[kp][2] = packh(r0.z, r1.z); ur[kp][3] = packh(r0.w, r1.w);
    }
    for (int kp = 96; kp < 128; kp++) {
      const float4 r0 = *(const float4*)(U + (2 * kp) * 1024 + c0);
      const float4 r1 = *(const float4*)(U + (2 * kp + 1) * 1024 + c0);
      ulds[kp - 96][c0]     = packh(r0.x, r1.x);
      ulds[kp - 96][c0 + 1] = packh(r0.y, r1.y);
      ulds[kp - 96][c0 + 2] = packh(r0.z, r1.z);
      ulds[kp - 96][c0 + 3] = packh(r0.w, r1.w);
    }
  } else {
    const u16* U = (const u16*)Uraw;
#pragma unroll
    for (int kp = 0; kp < 96; kp++) {
      const ushort4 r0 = *(const ushort4*)(U + (2 * kp) * 1024 + c0);
      const ushort4 r1 = *(const ushort4*)(U + (2 * kp + 1) * 1024 + c0);
      ur[kp][0] = packh(b2f(r0.x), b2f(r1.x)); ur[kp][1] = packh(b2f(r0.y), b2f(r1.y));
      ur[kp][2] = packh(b2f(r0.z), b2f(r1.z)); ur[kp][3] = packh(b2f(r0.w), b2f(r1.w));
    }
    for (int kp = 96; kp < 128; kp++) {
      const ushort4 r0 = *(const ushort4*)(U + (2 * kp) * 1024 + c0);
      const ushort4 r1 = *(const ushort4*)(U + (2 * kp + 1) * 1024 + c0);
      ulds[kp - 96][c0]     = packh(b2f(r0.x), b2f(r1.x));
      ulds[kp - 96][c0 + 1] = packh(b2f(r0.y), b2f(r1.y));
      ulds[kp - 96][c0 + 2] = packh(b2f(r0.z), b2f(r1.z));
      ulds[kp - 96][c0 + 3] = packh(b2f(r0.w), b2f(r1.w));
    }
  }
  msk[tid] = toks[b * 256 + tid];
  if (tid < 128) hp[tid] = 0u;
  float cReg = 0.f, hReg = 0.f;
  float4 xwv = *(const float4*)(xw + (dir ? 255 : 0) * 1024 + c0);
  __syncthreads();

  for (int s = 0; s < LSEQ; s++) {
    const int t = dir ? (255 - s) : s;
    const int tn = dir ? (s < 255 ? 254 - s : 0) : (s < 255 ? s + 1 : 255);
    float a0 = xwv.x, a1 = xwv.y, a2 = xwv.z, a3 = xwv.w;
    const float4 xwn = *(const float4*)(xw + tn * 1024 + c0);  // next-step prefetch
    // ---- z = xw + h @ U over 128 k-pairs ----
#pragma unroll
    for (int kp = 0; kp < 96; kp++) {
      const u32 h2 = hp[kp];
      a0 = dot2f(h2, ur[kp][0], a0); a1 = dot2f(h2, ur[kp][1], a1);
      a2 = dot2f(h2, ur[kp][2], a2); a3 = dot2f(h2, ur[kp][3], a3);
    }
#pragma unroll
    for (int kp = 0; kp < 32; kp++) {
      const u32 h2 = hp[96 + kp];
      const uint4 uu = *(const uint4*)&ulds[kp][c0];
      a0 = dot2f(h2, uu.x, a0); a1 = dot2f(h2, uu.y, a1);
      a2 = dot2f(h2, uu.z, a2); a3 = dot2f(h2, uu.w, a3);
    }
    zsh[c0] = a0; zsh[c0 + 1] = a1; zsh[c0 + 2] = a2; zsh[c0 + 3] = a3;
    __syncthreads();
    // ---- gates: unit u = tid ----
    const float zi = zsh[tid], zf = zsh[256 + tid];
    const float zg = zsh[512 + tid], zo = zsh[768 + tid];
    const float cn = sigm(zf) * cReg + sigm(zi) * tanh_fast(zg);
    const float hn = sigm(zo) * tanh_fast(cn);
    if (msk[t] != 0) { cReg = cn; hReg = hn; }
    hout[t * 512 + tid * 2 + b] = hReg;             // fire-and-forget global
    ((_Float16*)hp)[tid] = (_Float16)hReg;          // h for next step (fp16)
    xwv = xwn;
    __syncthreads();
  }
}

// ---------------- k_uvpq: fused relu(enc@W+b) -> (a,q) = @Wuv -> P,Q = @Wc ----------------
// grid (64 rowgroups, 3 heads), 8 rows per block.
struct HeadPack { const void* p[24]; };  // per head: uW,ub,vW,vb,uvW,uvb,cW,cb

__global__ __launch_bounds__(256) void k_uvpq(
    HeadPack pk, const void* __restrict__ etab, float* __restrict__ ws)
{
  __shared__ float encs_t[512][8];     // [h][row]
  __shared__ float usv_t[2][128][8];   // [u/v][col][row]
  __shared__ float apq[2][8][128];     // [a/q][row][col]
  __shared__ float wc[3072];
  const int tid = threadIdx.x, rgp = blockIdx.x, hd = blockIdx.y;
  const bool f32m = detect_f32(etab);
  const void* uW  = pk.p[hd * 8 + 0]; const void* ub  = pk.p[hd * 8 + 1];
  const void* vW  = pk.p[hd * 8 + 2]; const void* vb  = pk.p[hd * 8 + 3];
  const void* uvW = pk.p[hd * 8 + 4]; const void* uvb = pk.p[hd * 8 + 5];
  const void* cW  = pk.p[hd * 8 + 6];
  const int nout = (hd == 0) ? 1 : 24;
  for (int i = tid; i < 128 * nout; i += 256) wc[i] = ldf(cW, i, f32m);
  // load enc (transposed): encs_t[h][rr]; h layout is t-indexed [t][unit*2+b]
  for (int i = tid; i < 4096; i += 256) {
    const int h = i >> 3, rr = i & 7;
    const int row = rgp * 8 + rr, b = row >> 8, t = row & 255;
    encs_t[h][rr] = (h < 256)
        ? ws[HF_O + t * 512 + h * 2 + b]
        : ws[HB_O + t * 512 + (h - 256) * 2 + b];
  }
  __syncthreads();
  // phase 1: mat = tid>>7 (0=u,1=v), cs = tid&127
  {
    const int mat = tid >> 7, cs = tid & 127;
    const void* W = mat ? vW : uW;
    const float bias = ldf(mat ? vb : ub, cs, f32m);
    float acc[8];
#pragma unroll
    for (int rr = 0; rr < 8; rr++) acc[rr] = 0.f;
    if (f32m) {
      const float* Wf = (const float*)W;
      for (int k = 0; k < 512; k++) {
        const float wv = Wf[k * 128 + cs];
        const float4 e0 = *(const float4*)&encs_t[k][0];
        const float4 e1 = *(const float4*)&encs_t[k][4];
        acc[0] = fmaf(e0.x, wv, acc[0]); acc[1] = fmaf(e0.y, wv, acc[1]);
        acc[2] = fmaf(e0.z, wv, acc[2]); acc[3] = fmaf(e0.w, wv, acc[3]);
        acc[4] = fmaf(e1.x, wv, acc[4]); acc[5] = fmaf(e1.y, wv, acc[5]);
        acc[6] = fmaf(e1.z, wv, acc[6]); acc[7] = fmaf(e1.w, wv, acc[7]);
      }
    } else {
      const u16* Wf = (const u16*)W;
      for (int k = 0; k < 512; k++) {
        const float wv = b2f(Wf[k * 128 + cs]);
        const float4 e0 = *(const float4*)&encs_t[k][0];
        const float4 e1 = *(const float4*)&encs_t[k][4];
        acc[0] = fmaf(e0.x, wv, acc[0]); acc[1] = fmaf(e0.y, wv, acc[1]);
        acc[2] = fmaf(e0.z, wv, acc[2]); acc[3] = fmaf(e0.w, wv, acc[3]);
        acc[4] = fmaf(e1.x, wv, acc[4]); acc[5] = fmaf(e1.y, wv, acc[5]);
        acc[6] = fmaf(e1.z, wv, acc[6]); acc[7] = fmaf(e1.w, wv, acc[7]);
      }
    }
#pragma unroll
    for (int rr = 0; rr < 8; rr++)
      usv_t[mat][cs][rr] = fmaxf(acc[rr] + bias, 0.f);
  }
  __syncthreads();
  // phase 2: half = tid>>7 (0: a = u@Wuv[0:128]+buv, 1: q = v@Wuv[128:256])
  {
    const int half = tid >> 7, col = tid & 127;
    float acc[8];
#pragma unroll
    for (int rr = 0; rr < 8; rr++) acc[rr] = 0.f;
    if (f32m) {
      const float* Wf = (const float*)uvW;
      for (int k = 0; k < 128; k++) {
        const float wv = Wf[(half * 128 + k) * 128 + col];
        const float4 e0 = *(const float4*)&usv_t[half][k][0];
        const float4 e1 = *(const float4*)&usv_t[half][k][4];
        acc[0] = fmaf(e0.x, wv, acc[0]); acc[1] = fmaf(e0.y, wv, acc[1]);
        acc[2] = fmaf(e0.z, wv, acc[2]); acc[3] = fmaf(e0.w, wv, acc[3]);
        acc[4] = fmaf(e1.x, wv, acc[4]); acc[5] = fmaf(e1.y, wv, acc[5]);
        acc[6] = fmaf(e1.z, wv, acc[6]); acc[7] = fmaf(e1.w, wv, acc[7]);
      }
    } else {
      const u16* Wf = (const u16*)uvW;
      for (int k = 0; k < 128; k++) {
        const float wv = b2f(Wf[(half * 128 + k) * 128 + col]);
        const float4 e0 = *(const float4*)&usv_t[half][k][0];
        const float4 e1 = *(const float4*)&usv_t[half][k][4];
        acc[0] = fmaf(e0.x, wv, acc[0]); acc[1] = fmaf(e0.y, wv, acc[1]);
        acc[2] = fmaf(e0.z, wv, acc[2]); acc[3] = fmaf(e0.w, wv, acc[3]);
        acc[4] = fmaf(e1.x, wv, acc[4]); acc[5] = fmaf(e1.y, wv, acc[5]);
        acc[6] = fmaf(e1.z, wv, acc[6]); acc[7] = fmaf(e1.w, wv, acc[7]);
      }
    }
    const float bv = (half == 0) ? ldf(uvb, col, f32m) : 0.f;
#pragma unroll
    for (int rr = 0; rr < 8; rr++)
      apq[half][rr][col] = acc[rr] + bv;
  }
  __syncthreads();
  // phase 3: cls
  if (hd == 0) {
    if (tid < 16) {
      const int rr = tid >> 1, aq = tid & 1;
      float acc = 0.f;
      for (int e = 0; e < 128; e++) acc = fmaf(apq[aq][rr][e], wc[e], acc);
      const int row = rgp * 8 + rr;
      ws[(aq ? QEH_O : PEH_O) + row] = acc;
    }
  } else {
    const int PO = (hd == 1) ? PHH_O : PTT_O;
    const int QO = (hd == 1) ? QHH_O : QTT_O;
    for (int it = 0; it < 2; it++) {
      if (tid < 192) {
        const int task = it * 192 + tid;
        const int rr = task / 48, r2 = task % 48;
        const int aq = r2 / 24, o = r2 % 24;
        float acc = 0.f;
        for (int e = 0; e < 128; e++) acc = fmaf(apq[aq][rr][e], wc[e * 24 + o], acc);
        const int row = rgp * 8 + rr;
        ws[(aq ? QO : PO) + row * 24 + o] = acc;
      }
    }
  }
}

// ---------------- k_out: out[b,i,j] = act(P[b,j] + Q[b,i] + bc) ----------------
__global__ __launch_bounds__(256) void k_out(
    const void* __restrict__ bceh, const void* __restrict__ bchh,
    const void* __restrict__ bctt, const void* __restrict__ etab,
    const float* __restrict__ ws, void* __restrict__ outv)
{
  __shared__ float qh[24], qt[24];
  __shared__ float qe_s;
  __shared__ u32 sh[3072], st[3072];
  const bool f32m = detect_f32(etab);
  const int bi = blockIdx.x, b = bi >> 8, i = bi & 255;
  const int j = threadIdx.x;
  if (j < 24)       qh[j] = ws[QHH_O + (b * 256 + i) * 24 + j] + ldf(bchh, j, f32m);
  else if (j < 48)  qt[j - 24] = ws[QTT_O + (b * 256 + i) * 24 + (j - 24)] + ldf(bctt, j - 24, f32m);
  else if (j == 48) qe_s = ws[QEH_O + b * 256 + i] + ldf(bceh, 0, f32m);
  __syncthreads();
  {
    float v = ws[PEH_O + b * 256 + j] + qe_s;
    v = 1.f / (1.f + __expf(-v));
    if (f32m) ((float*)outv)[(b * 256 + i) * 256 + j] = v;
    else      ((u16*)outv)[(b * 256 + i) * 256 + j] = f2b(v);
  }
  float p[24];
  {
    const float* pp = ws + PHH_O + (b * 256 + j) * 24;
    float mx = -1e30f;
#pragma unroll
    for (int o = 0; o < 24; o++) { p[o] = pp[o] + qh[o]; mx = fmaxf(mx, p[o]); }
    float ssum = 0.f;
#pragma unroll
    for (int o = 0; o < 24; o++) { p[o] = __expf(p[o] - mx); ssum += p[o]; }
    const float inv = 1.f / ssum;
    if (f32m) {
      float* dst = (float*)outv + 131072 + (size_t)(bi * 256 + j) * 24;
#pragma unroll
      for (int m = 0; m < 6; m++)
        ((float4*)dst)[m] = make_float4(p[4*m]*inv, p[4*m+1]*inv, p[4*m+2]*inv, p[4*m+3]*inv);
    } else {
#pragma unroll
      for (int m = 0; m < 12; m++)
        sh[j * 12 + m] = ((u32)f2b(p[2*m+1] * inv) << 16) | (u32)f2b(p[2*m] * inv);
    }
  }
  {
    const float* pp = ws + PTT_O + (b * 256 + j) * 24;
    float mx = -1e30f;
#pragma unroll
    for (int o = 0; o < 24; o++) { p[o] = pp[o] + qt[o]; mx = fmaxf(mx, p[o]); }
    float ssum = 0.f;
#pragma unroll
    for (int o = 0; o < 24; o++) { p[o] = __expf(p[o] - mx); ssum += p[o]; }
    const float inv = 1.f / ssum;
    if (f32m) {
      float* dst = (float*)outv + 3276800 + (size_t)(bi * 256 + j) * 24;
#pragma unroll
      for (int m = 0; m < 6; m++)
        ((float4*)dst)[m] = make_float4(p[4*m]*inv, p[4*m+1]*inv, p[4*m+2]*inv, p[4*m+3]*inv);
    } else {
#pragma unroll
      for (int m = 0; m < 12; m++)
        st[j * 12 + m] = ((u32)f2b(p[2*m+1] * inv) << 16) | (u32)f2b(p[2*m] * inv);
    }
  }
  __syncthreads();
  if (!f32m) {
    u32* outu = (u32*)outv;
    const int baseH = 65536 + bi * 3072;     // eh = elems [0,131072)
    const int baseT = 1638400 + bi * 3072;   // tt starts at elem 3276800
#pragma unroll
    for (int m = 0; m < 12; m++) {
      outu[baseH + j + 256 * m] = sh[j + 256 * m];
      outu[baseT + j + 256 * m] = st[j + 256 * m];
    }
  }
}

extern "C" void kernel_launch(void* const* d_in, const int* in_sizes, int n_in,
                              void* d_out, int out_size, void* d_ws, size_t ws_size,
                              hipStream_t stream) {
  const int* toks = (const int*)d_in[0];
  const int* wrds = (const int*)d_in[1];
  float* ws = (float*)d_ws;

  k_embed_xw<<<dim3(256), dim3(256), 0, stream>>>(
      toks, wrds, d_in[3], d_in[4], d_in[5], d_in[7], d_in[8], d_in[10], ws);
  k_lstm<<<dim3(4), dim3(256), 0, stream>>>(toks, d_in[6], d_in[9], d_in[3], ws);
  HeadPack pk;
  for (int h = 0; h < 3; h++)
    for (int a = 0; a < 8; a++)
      pk.p[h * 8 + a] = d_in[11 + h * 8 + a];
  k_uvpq<<<dim3(64, 3), dim3(256), 0, stream>>>(pk, d_in[3], ws);
  k_out<<<dim3(512), dim3(256), 0, stream>>>(
      d_in[18], d_in[26], d_in[34], d_in[3], ws, d_out);
}